// Round 7
// baseline (808.671 us; speedup 1.0000x reference)
//
#include <hip/hip_runtime.h>
#include <hip/hip_bf16.h>
#include <math.h>

// GraphConvLSTM: B=512, IN=256, H=128, T=100, N=22.
// Round 6 (resubmit; prior attempt hit GPU-broker timeout, never ran):
// FUSED single-phase step. 256 threads (4 waves), one barrier/step.
// Wave w owns cols 32w..32w+31. After 32x32x16 MFMA, lane(col,khalf) +
// partner lane^32 hold all 22 hw rows for that col: 12x shfl_xor(32) + 22
// cndmask redistribute in-register; A-mix + gates computed in the same wave
// (no hw LDS round-trip, no second barrier). Numerics unchanged from R5:
// fp16 W single + h hi/lo split, fp32 gates, shared-exp transcendentals.

#define B_   512
#define IN_  256
#define H_   128
#define T_   100
#define N_   22
#define NH   (N_ * H_)      // 2816
#define TNH  (T_ * NH)      // 281600
#define HP   136            // padded h row length in fp16 elems (272B rows)
#define THREADS 256
#define LOG2E 1.442695041f

typedef __attribute__((ext_vector_type(8)))  _Float16 half8_t;  // fp16x8 MFMA frag
typedef __attribute__((ext_vector_type(16))) float    f32x16;   // 32x32 accumulator

// D^{-1/2}: deg 13 for nodes 0,9; 5 for 3,6,12,15; 4 otherwise
#define D13 0.2773500981126146f
#define D5  0.4472135954999579f
#define D4  0.5f

__global__ void __launch_bounds__(THREADS, 2)
gclstm_kernel(const float* __restrict__ x,
              const float* __restrict__ wi_w, const float* __restrict__ wi_b,
              const float* __restrict__ wf_w, const float* __restrict__ wf_b,
              const float* __restrict__ wo_w, const float* __restrict__ wo_b,
              const float* __restrict__ wc_w, const float* __restrict__ wc_b,
              const float* __restrict__ gcn_w, const float* __restrict__ gcn_b,
              float* __restrict__ out)
{
    __shared__ __align__(16) _Float16 h_hi[32][HP];   // rows 22..31 stay zero
    __shared__ __align__(16) _Float16 h_lo[32][HP];
    __shared__ float xp_lds[4][H_];
    __shared__ __align__(16) float xrow[IN_];

    const int t     = threadIdx.x;      // 0..255
    const int b     = blockIdx.x;
    const int lane  = t & 63;
    const int wid   = t >> 6;           // wave 0..3, owns cols 32*wid..+31
    const int l31   = lane & 31;
    const int khalf = lane >> 5;        // 0: nodes 0..10, 1: nodes 11..21
    const bool k0   = (khalf == 0);
    const int col   = 32 * wid + l31;   // this lane's channel (ho)

    // ---- stage x row; zero h ----
    if (t < IN_ / 4) {
        reinterpret_cast<float4*>(xrow)[t] =
            reinterpret_cast<const float4*>(x + (size_t)b * IN_)[t];
    }
    for (int e = t; e < 32 * HP / 2; e += THREADS) ((int*)h_hi)[e] = 0;
    for (int e = t; e < 32 * HP / 2; e += THREADS) ((int*)h_lo)[e] = 0;
    __syncthreads();

    // ---- x projections: thread does gates mg2 (i|f) and mg2+2 (o|c) at ho2 ----
    {
        const int ho2 = t & (H_ - 1);
        const int mg2 = t >> 7;
        const float* wA = mg2 ? wf_w : wi_w;  const float* bA = mg2 ? wf_b : wi_b;
        const float* wB = mg2 ? wc_w : wo_w;  const float* bB = mg2 ? wc_b : wo_b;
        const float* rA = wA + (size_t)ho2 * IN_;
        const float* rB = wB + (size_t)ho2 * IN_;
        float accA = bA[ho2], accB = bB[ho2];
        #pragma unroll
        for (int k4 = 0; k4 < IN_ / 4; ++k4) {
            float4 xv = reinterpret_cast<const float4*>(xrow)[k4];
            float4 wv = reinterpret_cast<const float4*>(rA)[k4];
            accA += wv.x * xv.x + wv.y * xv.y + wv.z * xv.z + wv.w * xv.w;
            float4 uv = reinterpret_cast<const float4*>(rB)[k4];
            accB += uv.x * xv.x + uv.y * xv.y + uv.z * xv.z + uv.w * xv.w;
        }
        xp_lds[mg2][ho2]     = accA;
        xp_lds[mg2 + 2][ho2] = accB;
    }

    // ---- gcn_w B-fragments (fp16, persistent, 32 VGPRs) ----
    // B-frag (32x32x16): lane holds W[k = 16*kk + 8*khalf + i][col]
    half8_t Bf[8];
    #pragma unroll
    for (int kk = 0; kk < 8; ++kk) {
        #pragma unroll
        for (int i = 0; i < 8; ++i) {
            Bf[kk][i] = (_Float16)gcn_w[(16 * kk + 8 * khalf + i) * H_ + col];
        }
    }
    __syncthreads();

    // ---- per-lane step-invariant gate constants (col = this lane's ho) ----
    const float gb  = gcn_b[col];
    const float Ei  = __builtin_exp2f(-LOG2E * (xp_lds[0][col] + gb));
    const float Ef  = __builtin_exp2f(-LOG2E * (xp_lds[1][col] + gb));
    const float Eo  = __builtin_exp2f(-LOG2E * (xp_lds[2][col] + gb));
    const float E2c = __builtin_exp2f(-2.0f * LOG2E * (xp_lds[3][col] + gb));

    // step-invariant per-slot constants (node = slot + 11*khalf)
    const float A1_0 = k0 ? D13 : D4;  const float A2_0 = k0 ? 3.0f * D13 : D4;
    const float A1_1 = k0 ? D4 : D5;
    const float A1_3 = k0 ? D5 : D4;
    const float A1_4 = k0 ? D4 : D5;
    const float A1_6 = k0 ? D5 : D4;
    const float A1_9 = k0 ? D13 : D4;  const float A2_9 = k0 ? 3.0f * D13 : D4;

    float c_reg[11];
    #pragma unroll
    for (int i = 0; i < 11; ++i) c_reg[i] = 0.0f;

    const int nb = k0 ? 0 : 11;                      // node base for this lane
    _Float16* hhp = &h_hi[0][0] + nb * HP + col;
    _Float16* hlp = &h_lo[0][0] + nb * HP + col;
    float* outb = out + (size_t)b * TNH + nb * H_ + col;

    for (int step = 0; step < T_; ++step) {
        // ---- MFMA: HW = (hh+hl) @ W, two independent chains ----
        f32x16 accA = (f32x16)(0.0f);
        f32x16 accB = (f32x16)(0.0f);
        #pragma unroll
        for (int kk = 0; kk < 8; ++kk) {
            const int ko = 16 * kk + 8 * khalf;
            const half8_t Ah = *reinterpret_cast<const half8_t*>(&h_hi[l31][ko]);
            const half8_t Al = *reinterpret_cast<const half8_t*>(&h_lo[l31][ko]);
            accA = __builtin_amdgcn_mfma_f32_32x32x16_f16(Ah, Bf[kk], accA, 0, 0, 0);
            accB = __builtin_amdgcn_mfma_f32_32x32x16_f16(Al, Bf[kk], accB, 0, 0, 0);
        }
        // reg 4q+i holds hw[row = 8q + 4*khalf + i][col]; q=3 rows are junk
        float hw[12];
        #pragma unroll
        for (int s = 0; s < 12; ++s) hw[s] = accA[s] + accB[s];

        // ---- redistribute: partner lane (^32) holds the other khalf's rows ----
        float oth[12];
        #pragma unroll
        for (int s = 0; s < 12; ++s) oth[s] = __shfl_xor(hw[s], 32, 64);
        // sel0[s] = rows 8q+i (k-bit 0), sel1[s] = rows 8q+4+i (k-bit 1)
        float sel0[12], sel1[10];
        #pragma unroll
        for (int s = 0; s < 12; ++s) sel0[s] = k0 ? hw[s] : oth[s];
        #pragma unroll
        for (int s = 0; s < 10; ++s) sel1[s] = k0 ? oth[s] : hw[s];

        // tt[row] = DINV[row] * hw[row]
        const float tt0  = sel0[0] * D13, tt1  = sel0[1] * D4, tt2  = sel0[2] * D4;
        const float tt3  = sel0[3] * D5,  tt4  = sel1[0] * D4, tt5  = sel1[1] * D4;
        const float tt6  = sel1[2] * D5,  tt7  = sel1[3] * D4, tt8  = sel0[4] * D4;
        const float tt9  = sel0[5] * D13, tt10 = sel0[6] * D4, tt11 = sel0[7] * D4;
        const float tt12 = sel1[4] * D5,  tt13 = sel1[5] * D4, tt14 = sel1[6] * D4;
        const float tt15 = sel1[7] * D5,  tt16 = sel0[8] * D4, tt17 = sel0[9] * D4;
        const float tt18 = sel0[10] * D4, tt19 = sel0[11] * D4;
        const float tt20 = sel1[8] * D4,  tt21 = sel1[9] * D4;

        const float S0 = tt0 + tt2 + tt5 + tt8 + tt11;
        const float S1 = tt0 + tt1 + tt4 + tt7 + tt10;
        const float S2 = tt0 + tt3 + tt6 + tt9 + tt12 + tt15;
        const float S3 = tt9 + tt14 + tt17 + tt19 + tt21;
        const float S4 = tt9 + tt13 + tt16 + tt18 + tt20;
        const float SAB = S0 + S1 + S2;
        const float SCD = S2 + S3 + S4;

        float* outs = outb + (size_t)step * NH;

        #define UPD(nn, A1v, A2v, SSv, TMYv) {                                  \
            const float g   = (A1v) * (SSv) - (A2v) * (TMYv);                   \
            const float E   = __builtin_exp2f(-LOG2E * g);                      \
            const float it  = __builtin_amdgcn_rcpf(1.0f + E * Ei);             \
            const float ft  = __builtin_amdgcn_rcpf(1.0f + E * Ef);             \
            const float ot  = __builtin_amdgcn_rcpf(1.0f + E * Eo);             \
            const float e2  = fminf(E * E * E2c, 1e30f);                        \
            const float ct  = (1.0f - e2) * __builtin_amdgcn_rcpf(1.0f + e2);   \
            const float cn  = ft * c_reg[nn] + it * ct;                         \
            c_reg[nn] = cn;                                                     \
            const float e2n = fminf(__builtin_exp2f(-2.0f * LOG2E * cn), 1e30f);\
            const float th  = (1.0f - e2n) * __builtin_amdgcn_rcpf(1.0f + e2n); \
            const float hn  = ot * th;                                          \
            outs[(nn) * H_] = hn;                                               \
            const _Float16 hh = (_Float16)hn;                                   \
            hhp[(nn) * HP] = hh;                                                \
            hlp[(nn) * HP] = (_Float16)(hn - (float)hh);                        \
        }

        UPD(0,  A1_0, A2_0, k0 ? SAB : S0, k0 ? tt0  : tt11)
        UPD(1,  A1_1, A1_1, k0 ? S1  : S2, k0 ? tt1  : tt12)
        UPD(2,  D4,   D4,   k0 ? S0  : S4, k0 ? tt2  : tt13)
        UPD(3,  A1_3, A1_3, k0 ? S2  : S3, k0 ? tt3  : tt14)
        UPD(4,  A1_4, A1_4, k0 ? S1  : S2, k0 ? tt4  : tt15)
        UPD(5,  D4,   D4,   k0 ? S0  : S4, k0 ? tt5  : tt16)
        UPD(6,  A1_6, A1_6, k0 ? S2  : S3, k0 ? tt6  : tt17)
        UPD(7,  D4,   D4,   k0 ? S1  : S4, k0 ? tt7  : tt18)
        UPD(8,  D4,   D4,   k0 ? S0  : S3, k0 ? tt8  : tt19)
        UPD(9,  A1_9, A2_9, k0 ? SCD : S4, k0 ? tt9  : tt20)
        UPD(10, D4,   D4,   k0 ? S1  : S3, k0 ? tt10 : tt21)
        #undef UPD

        __syncthreads();   // h fully written -> next step's A-reads
    }
}

extern "C" void kernel_launch(void* const* d_in, const int* in_sizes, int n_in,
                              void* d_out, int out_size, void* d_ws, size_t ws_size,
                              hipStream_t stream) {
    const float* x     = (const float*)d_in[0];
    const float* wi_w  = (const float*)d_in[1];
    const float* wi_b  = (const float*)d_in[2];
    const float* wf_w  = (const float*)d_in[3];
    const float* wf_b  = (const float*)d_in[4];
    const float* wo_w  = (const float*)d_in[5];
    const float* wo_b  = (const float*)d_in[6];
    const float* wc_w  = (const float*)d_in[7];
    const float* wc_b  = (const float*)d_in[8];
    const float* gcn_w = (const float*)d_in[9];
    const float* gcn_b = (const float*)d_in[10];
    float* out = (float*)d_out;

    gclstm_kernel<<<dim3(B_), dim3(THREADS), 0, stream>>>(
        x, wi_w, wi_b, wf_w, wf_b, wo_w, wo_b, wc_w, wc_b, gcn_w, gcn_b, out);
}